// Round 2
// baseline (3873.409 us; speedup 1.0000x reference)
//
#include <hip/hip_runtime.h>
#include <hip/hip_bf16.h>

// Problem constants
#define BATCH 2048
#define HID 256
#define COND 128
#define NCH 64
#define MAXLEN 128
#define RDIM 256

// Workspace float offsets
#define WCAT_OFF 0        // [256 k][256 units][4 gates] combined (r,z share Wih+Whh; i_n; h_n)
#define WHH0_OFF 262144   // [256 k][256][4] step-0 matrix (Whh_r, Whh_z, Whh_n, 0)
#define WLH_OFF  524288   // [384 k][256] latent_to_hidden transposed
#define BCAT_OFF 638976   // [256][4] biases per unit (t>=1)
#define BCAT0_OFF 640000  // [256][4] biases per unit (t==0)

__global__ void prep_kernel(const float* __restrict__ W_lh,
                            const float* __restrict__ W_ih, const float* __restrict__ W_hh,
                            const float* __restrict__ b_ih, const float* __restrict__ b_hh,
                            float* __restrict__ ws) {
    int gid = blockIdx.x * blockDim.x + threadIdx.x;   // 0..98303
    if (gid < 384 * 256) {
        int k = gid >> 8, u = gid & 255;
        ws[WLH_OFF + gid] = W_lh[u * 384 + k];
    }
    if (gid < 65536) {
        int k = gid >> 8, u = gid & 255;
        float ir = W_ih[u * 256 + k], iz = W_ih[(256 + u) * 256 + k], inw = W_ih[(512 + u) * 256 + k];
        float hr = W_hh[u * 256 + k], hz = W_hh[(256 + u) * 256 + k], hnw = W_hh[(512 + u) * 256 + k];
        int base = WCAT_OFF + k * 1024 + u * 4;
        ws[base + 0] = ir + hr; ws[base + 1] = iz + hz; ws[base + 2] = inw; ws[base + 3] = hnw;
        base = WHH0_OFF + k * 1024 + u * 4;
        ws[base + 0] = hr; ws[base + 1] = hz; ws[base + 2] = hnw; ws[base + 3] = 0.0f;
    }
    if (gid < 256) {
        int u = gid;
        float bir = b_ih[u], biz = b_ih[256 + u];
        float bhr = b_hh[u], bhz = b_hh[256 + u], bhn = b_hh[512 + u];
        int base = BCAT_OFF + u * 4;
        ws[base + 0] = bir + bhr; ws[base + 1] = biz + bhz; ws[base + 2] = b_ih[512 + u]; ws[base + 3] = bhn;
        base = BCAT0_OFF + u * 4;
        ws[base + 0] = bir + bhr; ws[base + 1] = biz + bhz; ws[base + 2] = bhn; ws[base + 3] = 0.0f;
    }
}

__device__ __forceinline__ float sigm(float x)   { return 1.0f / (1.0f + __expf(-x)); }
__device__ __forceinline__ float tanh_f(float x) { return 1.0f - 2.0f / (1.0f + __expf(2.0f * x)); }

// 256 workgroups x 1024 threads (16 waves = 4 waves/SIMD).
// wg owns 8 batch rows. Thread (u = tid&255, q = tid>>8):
//   - all threads: GEMM partial over k in [q*64, q*64+64) for unit u (4 gates x 8 rows)
//   - q>0 write partials to LDS buffer; q==0 reduces + epilogue + h update
//   - threads tid>=512 additionally compute prev-step logits (pipelined 1 behind)
__global__ __launch_bounds__(1024, 4)
void gru_persist(const float* __restrict__ z, const float* __restrict__ xc,
                 const float* __restrict__ b_lh, const float* __restrict__ b_ih,
                 const float* __restrict__ W_out, const float* __restrict__ b_out_g,
                 const float* __restrict__ ws, float* __restrict__ out) {
    __shared__ __align__(16) float lds_h[8 * 256];     // hidden state, 8 rows (8 KB)
    __shared__ __align__(16) float4 bufv[3 * 8 * 256]; // partial sums (96 KB); head reused for zc

    const int tid = threadIdx.x;
    const int u   = tid & 255;     // hidden unit
    const int q   = tid >> 8;      // k-quarter
    const int b0  = blockIdx.x * 8;

    // ---- stage zc = [z | x_cond] rows b0..b0+7 into bufv-as-float [i][384]
    float* zcs = (float*)bufv;
    for (int idx = tid; idx < 8 * 384; idx += 1024) {
        int i = idx / 384, k = idx - i * 384;
        zcs[idx] = (k < 256) ? z[(b0 + i) * 256 + k] : xc[(b0 + i) * 128 + (k - 256)];
    }
    __syncthreads();

    // ---- h0 = zc @ W_lh^T + b_lh  (q==0 threads only; one-time cost)
    float h_own[8];
    if (q == 0) {
        float acc[8];
        float blh = b_lh[u];
#pragma unroll
        for (int i = 0; i < 8; i++) acc[i] = blh;
        const float* Wlh = ws + WLH_OFF;
        for (int k4 = 0; k4 < 96; ++k4) {
            int k = k4 * 4;
            float w0 = Wlh[(k + 0) * 256 + u];
            float w1 = Wlh[(k + 1) * 256 + u];
            float w2 = Wlh[(k + 2) * 256 + u];
            float w3 = Wlh[(k + 3) * 256 + u];
#pragma unroll
            for (int i = 0; i < 8; i++) {
                const float4 hv = *(const float4*)&zcs[i * 384 + k];
                acc[i] += hv.x * w0 + hv.y * w1 + hv.z * w2 + hv.w * w3;
            }
        }
#pragma unroll
        for (int i = 0; i < 8; i++) { h_own[i] = acc[i]; lds_h[i * 256 + u] = acc[i]; }
    }
    __syncthreads();   // zc reads done, h0 visible, bufv free

    const float4* Wcat = (const float4*)(ws + WCAT_OFF);   // [k][unit] float4 of gates
    const float4* Whh0 = (const float4*)(ws + WHH0_OFF);
    const float4  bc1  = ((const float4*)(ws + BCAT_OFF))[u];
    const float4  bc0  = ((const float4*)(ws + BCAT0_OFF))[u];
    const float   bin_c = b_ih[512 + u];
    const int kbase = q * 64;

    // logits role: threads 512..1023 -> (o, r); one output column, one row each
    const int lo_o = tid & 63;
    const int lo_r = (tid - 512) >> 6;                 // valid when tid>=512 (0..7)
    const float bout = (tid >= 512) ? b_out_g[lo_o] : 0.0f;
    const float4* Woutv = (const float4*)(W_out);      // [o][256] row-major, float4 over k
    const float4* ldshv = (const float4*)lds_h;
    float* outp = out + (long)b0 * MAXLEN * NCH;

    for (int st = 0; st < MAXLEN; ++st) {
        const float4* Wp = (st == 0) ? Whh0 : Wcat;
        float ax[8], ay[8], az[8], aw[8];
        if (q == 0) {
            const float4 bc = (st == 0) ? bc0 : bc1;
#pragma unroll
            for (int i = 0; i < 8; i++) { ax[i] = bc.x; ay[i] = bc.y; az[i] = bc.z; aw[i] = bc.w; }
        } else {
#pragma unroll
            for (int i = 0; i < 8; i++) { ax[i] = 0.0f; ay[i] = 0.0f; az[i] = 0.0f; aw[i] = 0.0f; }
        }

        // ---- GEMM partial over this thread's k-quarter
#pragma unroll 2
        for (int k4 = 0; k4 < 16; ++k4) {
            int k = kbase + k4 * 4;
            float4 w0 = Wp[(k + 0) * 256 + u];
            float4 w1 = Wp[(k + 1) * 256 + u];
            float4 w2 = Wp[(k + 2) * 256 + u];
            float4 w3 = Wp[(k + 3) * 256 + u];
#pragma unroll
            for (int i = 0; i < 8; i++) {
                const float4 hv = *(const float4*)&lds_h[i * 256 + k];
                ax[i] += hv.x * w0.x; ay[i] += hv.x * w0.y; az[i] += hv.x * w0.z; aw[i] += hv.x * w0.w;
                ax[i] += hv.y * w1.x; ay[i] += hv.y * w1.y; az[i] += hv.y * w1.z; aw[i] += hv.y * w1.w;
                ax[i] += hv.z * w2.x; ay[i] += hv.z * w2.y; az[i] += hv.z * w2.z; aw[i] += hv.z * w2.w;
                ax[i] += hv.w * w3.x; ay[i] += hv.w * w3.y; az[i] += hv.w * w3.z; aw[i] += hv.w * w3.w;
            }
        }

        // ---- partial writeback (q>0), coalesced float4
        if (q) {
#pragma unroll
            for (int i = 0; i < 8; i++)
                bufv[(q - 1) * 2048 + i * 256 + u] = make_float4(ax[i], ay[i], az[i], aw[i]);
        }

        // ---- pipelined logits of PREVIOUS hn (lds_h), overlapped with reduce wait
        if (tid >= 512 && st > 0) {
            float l = bout;
#pragma unroll 4
            for (int k4 = 0; k4 < 64; ++k4) {
                const float4 w = Woutv[lo_o * 64 + k4];
                const float4 h = ldshv[lo_r * 64 + k4];
                l += h.x * w.x + h.y * w.y + h.z * w.z + h.w * w.w;
            }
            outp[(long)lo_r * MAXLEN * NCH + (st - 1) * NCH + lo_o] = l;
        }

        __syncthreads();   // barrier A: partials in bufv, all lds_h readers done

        // ---- reduce + epilogue + h update (q==0 only)
        if (q == 0) {
#pragma unroll
            for (int qq = 0; qq < 3; ++qq)
#pragma unroll
                for (int i = 0; i < 8; ++i) {
                    const float4 p = bufv[qq * 2048 + i * 256 + u];
                    ax[i] += p.x; ay[i] += p.y; az[i] += p.z; aw[i] += p.w;
                }
            float hn_[8];
            if (st == 0) {
#pragma unroll
                for (int i = 0; i < 8; i++) {
                    float r = sigm(ax[i]); float uu = sigm(ay[i]);
                    float n = tanh_f(bin_c + r * az[i]);   // i_n = b_ih_n (x = 0)
                    hn_[i] = (1.0f - uu) * n + uu * h_own[i];
                }
            } else {
#pragma unroll
                for (int i = 0; i < 8; i++) {
                    float r = sigm(ax[i]); float uu = sigm(ay[i]);
                    float n = tanh_f(az[i] + r * aw[i]);
                    hn_[i] = (1.0f - uu) * n + uu * h_own[i];
                }
            }
#pragma unroll
            for (int i = 0; i < 8; i++) { lds_h[i * 256 + u] = hn_[i]; h_own[i] = hn_[i]; }
        }
        __syncthreads();   // barrier B: new h visible
    }

    // ---- final logits (step MAXLEN-1)
    if (tid >= 512) {
        float l = bout;
#pragma unroll 4
        for (int k4 = 0; k4 < 64; ++k4) {
            const float4 w = Woutv[lo_o * 64 + k4];
            const float4 h = ldshv[lo_r * 64 + k4];
            l += h.x * w.x + h.y * w.y + h.z * w.z + h.w * w.w;
        }
        outp[(long)lo_r * MAXLEN * NCH + (MAXLEN - 1) * NCH + lo_o] = l;
    }
}

extern "C" void kernel_launch(void* const* d_in, const int* in_sizes, int n_in,
                              void* d_out, int out_size, void* d_ws, size_t ws_size,
                              hipStream_t stream) {
    const float* z     = (const float*)d_in[0];
    const float* xcond = (const float*)d_in[1];
    const float* W_lh  = (const float*)d_in[2];
    const float* b_lh  = (const float*)d_in[3];
    const float* W_ih  = (const float*)d_in[4];
    const float* W_hh  = (const float*)d_in[5];
    const float* b_ih  = (const float*)d_in[6];
    const float* b_hh  = (const float*)d_in[7];
    const float* W_out = (const float*)d_in[8];
    const float* b_out = (const float*)d_in[9];
    float* out = (float*)d_out;
    float* ws  = (float*)d_ws;

    hipLaunchKernelGGL(prep_kernel, dim3(384), dim3(256), 0, stream,
                       W_lh, W_ih, W_hh, b_ih, b_hh, ws);
    hipLaunchKernelGGL(gru_persist, dim3(256), dim3(1024), 0, stream,
                       z, xcond, b_lh, b_ih, W_out, b_out, ws, out);
}

// Round 6
// 3332.883 us; speedup vs baseline: 1.1622x; 1.1622x over previous
//
#include <hip/hip_runtime.h>
#include <hip/hip_bf16.h>

// Problem constants
#define BATCH 2048
#define NCH 64
#define MAXLEN 128
#define RDIM 256

// Workspace float offsets
#define WCAT_OFF 0        // [256 k][256 u][4 gates] (r,z combined Wih+Whh; i_n; h_n)
#define WHH0_OFF 262144   // [256 k][256 u][4] step-0 (Whh_r, Whh_z, Whh_n, 0)
#define WLH_OFF  524288   // [384 k][256 u]
#define WOUT_OFF 622592   // [256 k][64 o] transposed
#define BCAT_OFF 638976   // [256 u][4]
#define BCAT0_OFF 640000  // [256 u][4]

__global__ void prep_kernel(const float* __restrict__ W_lh,
                            const float* __restrict__ W_ih, const float* __restrict__ W_hh,
                            const float* __restrict__ b_ih, const float* __restrict__ b_hh,
                            const float* __restrict__ W_out, float* __restrict__ ws) {
    int gid = blockIdx.x * blockDim.x + threadIdx.x;   // 0..98303
    if (gid < 384 * 256) {
        int k = gid >> 8, u = gid & 255;
        ws[WLH_OFF + gid] = W_lh[u * 384 + k];
    }
    if (gid < 65536) {
        int k = gid >> 8, u = gid & 255;
        float ir = W_ih[u * 256 + k], iz = W_ih[(256 + u) * 256 + k], inw = W_ih[(512 + u) * 256 + k];
        float hr = W_hh[u * 256 + k], hz = W_hh[(256 + u) * 256 + k], hnw = W_hh[(512 + u) * 256 + k];
        int base = WCAT_OFF + k * 1024 + u * 4;
        ws[base + 0] = ir + hr; ws[base + 1] = iz + hz; ws[base + 2] = inw; ws[base + 3] = hnw;
        base = WHH0_OFF + k * 1024 + u * 4;
        ws[base + 0] = hr; ws[base + 1] = hz; ws[base + 2] = hnw; ws[base + 3] = 0.0f;
    }
    if (gid < 16384) {
        int o = gid & 63, k = gid >> 6;
        ws[WOUT_OFF + k * 64 + o] = W_out[o * 256 + k];   // transpose to [k][o]
    }
    if (gid < 256) {
        int u = gid;
        float bir = b_ih[u], biz = b_ih[256 + u];
        float bhr = b_hh[u], bhz = b_hh[256 + u], bhn = b_hh[512 + u];
        int base = BCAT_OFF + u * 4;
        ws[base + 0] = bir + bhr; ws[base + 1] = biz + bhz; ws[base + 2] = b_ih[512 + u]; ws[base + 3] = bhn;
        base = BCAT0_OFF + u * 4;
        ws[base + 0] = bir + bhr; ws[base + 1] = biz + bhz; ws[base + 2] = bhn; ws[base + 3] = 0.0f;
    }
}

__device__ __forceinline__ float sigm(float x)   { return 1.0f / (1.0f + __expf(-x)); }
__device__ __forceinline__ float tanh_f(float x) { return 1.0f - 2.0f / (1.0f + __expf(2.0f * x)); }

// 256 wgs x 1024 threads (16 waves/CU = 4/SIMD, needs VGPR<=128 -> launch_bounds(1024,1)).
// wg owns 8 batch rows. Thread (u = tid&255, q = tid>>8):
//   GEMM: rows in rotated order (2q+jj)&7 over k-slice [q*64, q*64+64) -> own rows at slots 0,1
//   partials for slots 2..7 -> LDS; every thread epilogues its own 2 rows (distributed reduce)
//   logits: all threads compute half-k partials (coalesced W_out^T), combine after barrier
__global__ __launch_bounds__(1024, 1)
void gru_persist(const float* __restrict__ z, const float* __restrict__ xc,
                 const float* __restrict__ b_lh, const float* __restrict__ b_ih,
                 const float* __restrict__ b_out_g,
                 const float* __restrict__ ws, float* __restrict__ out) {
    __shared__ __align__(16) float lds_h[8 * 256];        // 8 KB
    __shared__ __align__(16) float4 pbufv[4 * 6 * 256];   // 96 KB partials (head reused for zc)
    __shared__ float lbuf[1024];                          // 4 KB logit partials

    const int tid = threadIdx.x;
    const int u   = tid & 255;
    const int q   = __builtin_amdgcn_readfirstlane(tid >> 8);   // wave-uniform -> SGPR
    const int b0  = blockIdx.x * 8;

    // ---- stage zc = [z | x_cond] rows b0..b0+7 into pbufv-as-float [i][384]
    float* zcs = (float*)pbufv;
    for (int idx = tid; idx < 8 * 384; idx += 1024) {
        int i = idx / 384, k = idx - i * 384;
        zcs[idx] = (k < 256) ? z[(b0 + i) * 256 + k] : xc[(b0 + i) * 128 + (k - 256)];
    }
    __syncthreads();

    // ---- h0 for own rows 2q, 2q+1 (distributed over all threads)
    float h_own0, h_own1;
    {
        float a0 = b_lh[u], a1 = a0;
        const float* Wlh = ws + WLH_OFF + u;
        const float* zr0 = zcs + (2 * q) * 384;
        const float* zr1 = zr0 + 384;
#pragma unroll 2
        for (int k4 = 0; k4 < 96; ++k4) {
            int k = 4 * k4;
            float w0 = Wlh[(k + 0) * 256];
            float w1 = Wlh[(k + 1) * 256];
            float w2 = Wlh[(k + 2) * 256];
            float w3 = Wlh[(k + 3) * 256];
            const float4 v0 = *(const float4*)(zr0 + k);
            const float4 v1 = *(const float4*)(zr1 + k);
            a0 += v0.x * w0 + v0.y * w1 + v0.z * w2 + v0.w * w3;
            a1 += v1.x * w0 + v1.y * w1 + v1.z * w2 + v1.w * w3;
        }
        h_own0 = a0; h_own1 = a1;
        lds_h[(2 * q) * 256 + u] = a0;
        lds_h[(2 * q + 1) * 256 + u] = a1;
    }
    __syncthreads();   // zc reads done, h0 visible, pbufv free

    const float4* Wcat  = (const float4*)(ws + WCAT_OFF);
    const float4* Whh0v = (const float4*)(ws + WHH0_OFF);
    const float4  bc1   = ((const float4*)(ws + BCAT_OFF))[u];
    const float4  bc0v  = ((const float4*)(ws + BCAT0_OFF))[u];
    const float   bin_c = b_ih[512 + u];

    int ro[8];   // slot jj -> LDS row offset of batch row (2q+jj)&7  (SGPRs: q scalar)
#pragma unroll
    for (int jj = 0; jj < 8; ++jj) ro[jj] = (((2 * q + jj) & 7) << 8);

    // logits-partial mapping: thread -> output p=tid>>1 (r=p>>6,o=p&63), k-half kh=tid&1
    const int lkh = tid & 1;
    const float* hrow_base = lds_h + ((tid >> 1) >> 6) * 256 + lkh * 128;
    const float* wcolT = ws + WOUT_OFF + lkh * 128 * 64 + ((tid >> 1) & 63);
    // combine mapping (tid<512): output (cr, co)
    const int co = tid & 63, cr = tid >> 6;
    const float bout = b_out_g[co];
    float* outp = out + (long)b0 * MAXLEN * NCH;

    for (int st = 0; st < MAXLEN; ++st) {
        const float4* Wp = st ? Wcat : Whh0v;
        float ax[8], ay[8], az[8], aw[8];
#pragma unroll
        for (int jj = 0; jj < 8; ++jj) { ax[jj] = 0.f; ay[jj] = 0.f; az[jj] = 0.f; aw[jj] = 0.f; }

        const float4* wbase = Wp + (q * 64) * 256 + u;
        const float*  hbase = lds_h + q * 64;

        // ---- GEMM over own k-slice (64 k), all 8 rows (rotated slots)
#pragma unroll 2
        for (int k4 = 0; k4 < 16; ++k4) {
            const float4 w0 = wbase[(4 * k4 + 0) * 256];
            const float4 w1 = wbase[(4 * k4 + 1) * 256];
            const float4 w2 = wbase[(4 * k4 + 2) * 256];
            const float4 w3 = wbase[(4 * k4 + 3) * 256];
#pragma unroll
            for (int jj = 0; jj < 8; ++jj) {
                const float4 hv = *(const float4*)(hbase + ro[jj] + 4 * k4);
                ax[jj] += hv.x * w0.x; ay[jj] += hv.x * w0.y; az[jj] += hv.x * w0.z; aw[jj] += hv.x * w0.w;
                ax[jj] += hv.y * w1.x; ay[jj] += hv.y * w1.y; az[jj] += hv.y * w1.z; aw[jj] += hv.y * w1.w;
                ax[jj] += hv.z * w2.x; ay[jj] += hv.z * w2.y; az[jj] += hv.z * w2.z; aw[jj] += hv.z * w2.w;
                ax[jj] += hv.w * w3.x; ay[jj] += hv.w * w3.y; az[jj] += hv.w * w3.z; aw[jj] += hv.w * w3.w;
            }
        }

        // ---- write partials for the 6 non-own rows (slot j+2 -> row (2q+2+j)&7)
        {
            float4* pb = pbufv + q * 6 * 256 + u;
#pragma unroll
            for (int j = 0; j < 6; ++j)
                pb[j * 256] = make_float4(ax[j + 2], ay[j + 2], az[j + 2], aw[j + 2]);
        }

        // ---- logits partial of PREVIOUS step's h (old lds_h), coalesced W_out^T
        if (st) {
            float l = 0.f;
#pragma unroll 8
            for (int kk = 0; kk < 128; ++kk) l += hrow_base[kk] * wcolT[kk * 64];
            lbuf[tid] = l;
        }

        __syncthreads();   // A: partials + logit-partials visible; all old-h reads done

        // ---- distributed reduce + epilogue for own rows (slots 0,1)
#pragma unroll
        for (int qq = 0; qq < 4; ++qq) {
            if (qq != q) {
                const int j0 = (2 * q - 2 * qq - 2) & 7;       // in {0,2,4}
                const float4 p0 = pbufv[(qq * 6 + j0) * 256 + u];
                const float4 p1 = pbufv[(qq * 6 + j0 + 1) * 256 + u];
                ax[0] += p0.x; ay[0] += p0.y; az[0] += p0.z; aw[0] += p0.w;
                ax[1] += p1.x; ay[1] += p1.y; az[1] += p1.z; aw[1] += p1.w;
            }
        }
        float hn0, hn1;
        if (st == 0) {
            float r0 = sigm(ax[0] + bc0v.x), z0 = sigm(ay[0] + bc0v.y);
            float n0 = tanh_f(bin_c + r0 * (az[0] + bc0v.z));
            hn0 = (1.f - z0) * n0 + z0 * h_own0;
            float r1 = sigm(ax[1] + bc0v.x), z1 = sigm(ay[1] + bc0v.y);
            float n1 = tanh_f(bin_c + r1 * (az[1] + bc0v.z));
            hn1 = (1.f - z1) * n1 + z1 * h_own1;
        } else {
            float r0 = sigm(ax[0] + bc1.x), z0 = sigm(ay[0] + bc1.y);
            float n0 = tanh_f(az[0] + bc1.z + r0 * (aw[0] + bc1.w));
            hn0 = (1.f - z0) * n0 + z0 * h_own0;
            float r1 = sigm(ax[1] + bc1.x), z1 = sigm(ay[1] + bc1.y);
            float n1 = tanh_f(az[1] + bc1.z + r1 * (aw[1] + bc1.w));
            hn1 = (1.f - z1) * n1 + z1 * h_own1;
        }
        lds_h[(2 * q) * 256 + u] = hn0;
        lds_h[(2 * q + 1) * 256 + u] = hn1;
        h_own0 = hn0; h_own1 = hn1;

        // ---- combine + store previous step's logits
        if (st && tid < 512) {
            float l = lbuf[2 * tid] + lbuf[2 * tid + 1] + bout;
            outp[(long)cr * MAXLEN * NCH + (st - 1) * NCH + co] = l;
        }
        __syncthreads();   // B: new h visible; lbuf consumed
    }

    // ---- final step's logits (from final lds_h)
    {
        float l = 0.f;
#pragma unroll 8
        for (int kk = 0; kk < 128; ++kk) l += hrow_base[kk] * wcolT[kk * 64];
        lbuf[tid] = l;
    }
    __syncthreads();
    if (tid < 512) {
        float l = lbuf[2 * tid] + lbuf[2 * tid + 1] + bout;
        outp[(long)cr * MAXLEN * NCH + (MAXLEN - 1) * NCH + co] = l;
    }
}

extern "C" void kernel_launch(void* const* d_in, const int* in_sizes, int n_in,
                              void* d_out, int out_size, void* d_ws, size_t ws_size,
                              hipStream_t stream) {
    const float* z     = (const float*)d_in[0];
    const float* xcond = (const float*)d_in[1];
    const float* W_lh  = (const float*)d_in[2];
    const float* b_lh  = (const float*)d_in[3];
    const float* W_ih  = (const float*)d_in[4];
    const float* W_hh  = (const float*)d_in[5];
    const float* b_ih  = (const float*)d_in[6];
    const float* b_hh  = (const float*)d_in[7];
    const float* W_out = (const float*)d_in[8];
    const float* b_out = (const float*)d_in[9];
    float* out = (float*)d_out;
    float* ws  = (float*)d_ws;

    hipLaunchKernelGGL(prep_kernel, dim3(384), dim3(256), 0, stream,
                       W_lh, W_ih, W_hh, b_ih, b_hh, W_out, ws);
    hipLaunchKernelGGL(gru_persist, dim3(256), dim3(1024), 0, stream,
                       z, xcond, b_lh, b_ih, b_out, ws, out);
}